// Round 1
// baseline (8290.337 us; speedup 1.0000x reference)
//
#include <hip/hip_runtime.h>
#include <math.h>

#define DI __device__ __forceinline__

DI float sigm(float x){ return 1.0f/(1.0f+expf(-x)); }
DI float lrelu(float x){ return x > 0.f ? x : 0.01f*x; }

template<int ACT>
DI float act_apply(float v){
    if (ACT == 1) return tanhf(v);
    if (ACT == 2) return lrelu(v);
    return v;
}

// ---------------- encoder conv: stride 2, 4x4, tanh ----------------
template<int CIN, int COUT>
__global__ __launch_bounds__(256)
void conv_enc_kernel(const float* __restrict__ in, const float* __restrict__ w,
                     const float* __restrict__ bias, float* __restrict__ out,
                     int N, int H, int OH)
{
    int idx = blockIdx.x*256 + threadIdx.x;
    int total = N*COUT*OH*OH;
    if (idx >= total) return;
    int ox = idx % OH; int t = idx / OH;
    int oy = t % OH;   t /= OH;
    int o  = t % COUT; int n = t / COUT;
    float acc = bias[o];
    const float* wp = w + o*CIN*16;
    const float* ip = in + ((size_t)n*CIN)*H*H + (oy*2)*H + ox*2;
    for (int c = 0; c < CIN; ++c) {
        const float* ipc = ip + c*H*H;
        const float* wpc = wp + c*16;
        #pragma unroll
        for (int ky = 0; ky < 4; ++ky)
            #pragma unroll
            for (int kx = 0; kx < 4; ++kx)
                acc += ipc[ky*H + kx] * wpc[ky*4 + kx];
    }
    out[idx] = tanhf(acc);
}

// ---------------- generic tiled GEMM: C = act(A @ B^T? + bias) ----------------
// A: [M,K] row-major.  BT ? B:[N,K] : B:[K,N].  C: [M,ldc]. bias[n / bias_div].
template<int BM,int BN,int BK,int TM,int TN,bool BT,int ACT,bool ACC>
__global__ __launch_bounds__((BM/TM)*(BN/TN))
void gemm_kernel(const float* __restrict__ A, const float* __restrict__ Bm,
                 const float* __restrict__ bias, float* __restrict__ C,
                 int M, int N, int K, int ldc, int bias_div)
{
    constexpr int THREADS = (BM/TM)*(BN/TN);
    constexpr int PAD = 4;
    __shared__ float As[BK][BM+PAD];
    __shared__ float Bs[BK][BN+PAD];
    int tid = threadIdx.x;
    int m0 = blockIdx.y * BM, n0 = blockIdx.x * BN;
    constexpr int NTX = BN/TN;
    int tx = tid % NTX, ty = tid / NTX;
    float acc[TM][TN];
    #pragma unroll
    for (int i=0;i<TM;++i)
        #pragma unroll
        for (int j=0;j<TN;++j) acc[i][j] = 0.f;

    for (int k0 = 0; k0 < K; k0 += BK) {
        for (int e = tid; e < BM*BK; e += THREADS) {
            int k = e % BK, m = e / BK;
            float v = 0.f;
            if (m0+m < M) v = A[(size_t)(m0+m)*K + k0+k];
            As[k][m] = v;
        }
        if (BT) {
            for (int e = tid; e < BN*BK; e += THREADS) {
                int k = e % BK, n = e / BK;
                float v = 0.f;
                if (n0+n < N) v = Bm[(size_t)(n0+n)*K + k0+k];
                Bs[k][n] = v;
            }
        } else {
            for (int e = tid; e < BN*BK; e += THREADS) {
                int n = e % BN, k = e / BN;
                float v = 0.f;
                if (n0+n < N) v = Bm[(size_t)(k0+k)*N + n0+n];
                Bs[k][n] = v;
            }
        }
        __syncthreads();
        #pragma unroll 4
        for (int k = 0; k < BK; ++k) {
            float a[TM], b[TN];
            #pragma unroll
            for (int i=0;i<TM;++i) a[i] = As[k][ty*TM+i];
            #pragma unroll
            for (int j=0;j<TN;++j) b[j] = Bs[k][tx*TN+j];
            #pragma unroll
            for (int i=0;i<TM;++i)
                #pragma unroll
                for (int j=0;j<TN;++j)
                    acc[i][j] += a[i]*b[j];
        }
        __syncthreads();
    }
    #pragma unroll
    for (int i=0;i<TM;++i) {
        int m = m0 + ty*TM + i;
        if (m >= M) continue;
        #pragma unroll
        for (int j=0;j<TN;++j) {
            int n = n0 + tx*TN + j;
            if (n >= N) continue;
            float v = acc[i][j] + bias[n / bias_div];
            if (ACC) v += C[(size_t)m*ldc + n];
            C[(size_t)m*ldc + n] = act_apply<ACT>(v);
        }
    }
}

// ---------------- small helpers ----------------
__global__ __launch_bounds__(256)
void addvec_kernel(const float* __restrict__ a, const float* __restrict__ b,
                   float* __restrict__ o, int n)
{
    int i = blockIdx.x*256 + threadIdx.x;
    if (i < n) o[i] = a[i] + b[i];
}

__global__ __launch_bounds__(64)
void concat_action_kernel(const float* __restrict__ action, float* __restrict__ z)
{
    int i = blockIdx.x*64 + threadIdx.x;
    if (i < 50*30) { int b = i/30, k = i%30; z[b*512 + 482 + k] = action[i]; }
}

__global__ __launch_bounds__(64)
void reward_kernel(const float* __restrict__ z, const float* __restrict__ w,
                   const float* __restrict__ b, float* __restrict__ out)
{
    int bi = threadIdx.x;
    if (bi < 50) {
        float acc = b[0];
        for (int k = 0; k < 512; ++k) acc += z[bi*512 + k] * w[k];
        out[bi] = acc;
    }
}

__global__ __launch_bounds__(256)
void lstm_gates_kernel(const float* __restrict__ g, const float* __restrict__ c_prev,
                       float* __restrict__ c_out, float* __restrict__ h_out,
                       float* __restrict__ outs_t)
{
    int idx = blockIdx.x*256 + threadIdx.x;
    if (idx >= 50*1024) return;
    int b = idx >> 10, j = idx & 1023;
    const float* gr = g + b*4096;
    float gi = gr[j], gf = gr[1024+j], gg = gr[2048+j], go = gr[3072+j];
    float cp = c_prev[idx];
    float c = sigm(gf)*cp + sigm(gi)*tanhf(gg);
    float h = sigm(go)*tanhf(c);
    c_out[idx] = c; h_out[idx] = h; outs_t[idx] = h;
}

// ---------------- transposed conv (stride 2), direct gather ----------------
// out[n,o,y,x] = bias[o] + sum_{c,ky,kx} in[n,c,(y-ky)/2,(x-kx)/2] * w[c,o,ky,kx]
// Each thread computes 8 consecutive x for one (n,o,y). x0 always even.
template<int CIN,int COUT,int KS,int ACT>
__global__ __launch_bounds__(256)
void deconv_kernel(const float* __restrict__ in, const float* __restrict__ w,
                   const float* __restrict__ bias, float* __restrict__ out,
                   int N, int Hin, int Hout)
{
    int nx8 = (Hout + 7) >> 3;
    int idx = blockIdx.x*256 + threadIdx.x;
    int total = N*COUT*Hout*nx8;
    if (idx >= total) return;
    int cx = idx % nx8; int t = idx / nx8;
    int y  = t % Hout;  t /= Hout;
    int o  = t % COUT;  int n = t / COUT;
    int x0 = cx*8;
    float acc[8];
    float bv = bias[o];
    #pragma unroll
    for (int j=0;j<8;++j) acc[j] = bv;
    int ixb = (x0 >> 1) - 2;

    #pragma unroll
    for (int ky = 0; ky < KS; ++ky) {
        int yy = y - ky;
        if (yy & 1) continue;
        int iy = yy >> 1;
        if (iy < 0 || iy >= Hin) continue;
        const float* iprow = in + (((size_t)n*CIN)*Hin + iy)*Hin;
        const float* wrow  = w + (o*KS + ky)*KS;
        for (int c = 0; c < CIN; ++c) {
            const float* ip = iprow + (size_t)c*Hin*Hin;
            const float* wp = wrow + (size_t)c*COUT*KS*KS;
            float r[6];
            #pragma unroll
            for (int t2 = 0; t2 < 6; ++t2) {
                int ix = ixb + t2;
                r[t2] = (ix >= 0 && ix < Hin) ? ip[ix] : 0.f;
            }
            #pragma unroll
            for (int kx = 0; kx < KS; ++kx) {
                float wv = wp[kx];
                #pragma unroll
                for (int j = 0; j < 8; ++j) {
                    if (((j ^ kx) & 1) == 0) {
                        int rel = (j - kx) >> 1;     // exact: (j-kx) even
                        acc[j] += wv * r[rel + 2];
                    }
                }
            }
        }
    }
    size_t ob = (((size_t)n*COUT + o)*Hout + y)*Hout + x0;
    #pragma unroll
    for (int j = 0; j < 8; ++j)
        if (x0 + j < Hout) out[ob + j] = act_apply<ACT>(acc[j]);
}

// ---------------- launch ----------------
extern "C" void kernel_launch(void* const* d_in, const int* in_sizes, int n_in,
                              void* d_out, int out_size, void* d_ws, size_t ws_size,
                              hipStream_t stream)
{
    const float* x       = (const float*)d_in[0];
    const float* action  = (const float*)d_in[1];
    const float* h0      = (const float*)d_in[2];
    const float* c0      = (const float*)d_in[3];
    const float* conv1_w = (const float*)d_in[4];  const float* conv1_b = (const float*)d_in[5];
    const float* conv2_w = (const float*)d_in[6];  const float* conv2_b = (const float*)d_in[7];
    const float* conv3_w = (const float*)d_in[8];  const float* conv3_b = (const float*)d_in[9];
    const float* conv4_w = (const float*)d_in[10]; const float* conv4_b = (const float*)d_in[11];
    const float* fc1_w   = (const float*)d_in[12]; const float* fc1_b   = (const float*)d_in[13];
    const float* fc2_w   = (const float*)d_in[14]; const float* fc2_b   = (const float*)d_in[15];
    const float* w_ih    = (const float*)d_in[16]; const float* w_hh    = (const float*)d_in[17];
    const float* b_ih    = (const float*)d_in[18]; const float* b_hh    = (const float*)d_in[19];
    const float* fcsd_w  = (const float*)d_in[20]; const float* fcsd_b  = (const float*)d_in[21];
    const float* d1_w    = (const float*)d_in[22]; const float* d1_b    = (const float*)d_in[23];
    const float* d2_w    = (const float*)d_in[24]; const float* d2_b    = (const float*)d_in[25];
    const float* d3_w    = (const float*)d_in[26]; const float* d3_b    = (const float*)d_in[27];
    const float* d4_w    = (const float*)d_in[28]; const float* d4_b    = (const float*)d_in[29];
    const float* fc5_w   = (const float*)d_in[30]; const float* fc5_b   = (const float*)d_in[31];
    float* out = (float*)d_out;
    float* ws  = (float*)d_ws;

    // workspace layout (floats)
    float* a1   = ws;                    // [50,32,31,31]  1,537,600
    float* a2   = a1 + 1537600;          // [50,64,14,14]  627,200
    float* a3   = a2 + 627200;           // [50,128,6,6]   230,400
    float* flat = a3 + 230400;           // [50,1024]      51,200
    float* z    = flat + 51200;          // [50,512]       25,600
    float* fc2o = z + 25600;             // [50,1024]      51,200
    float* g    = fc2o + 51200;          // [50,4096]      204,800
    float* hbuf = g + 204800;            // [50,1024]
    float* cbuf = hbuf + 51200;          // [50,1024]
    float* outs = cbuf + 51200;          // [17,50,1024]   870,400
    float* hd   = outs + 870400;         // [850,1024]     870,400
    float* wsum = hd + 870400;           // [4096,1024]    4,194,304
    float* bsum = wsum + 4194304;        // [4096]
    float* y1   = bsum + 4096;           // [850,128,5,5]  2,720,000
    float* y2   = y1 + 2720000;          // [850,64,13,13] 9,193,600
    float* y3   = y2 + 9193600;          // [850,32,30,30] 24,480,000

    const int B = 50;

    // wsum = w_ih + w_hh ; bsum = b_ih + b_hh  (LSTM feeds h back as x for t>=1)
    addvec_kernel<<<(4194304+255)/256, 256, 0, stream>>>(w_ih, w_hh, wsum, 4194304);
    addvec_kernel<<<(4096+255)/256, 256, 0, stream>>>(b_ih, b_hh, bsum, 4096);

    // encoder
    conv_enc_kernel<1,32><<<(B*32*31*31+255)/256, 256, 0, stream>>>(x, conv1_w, conv1_b, a1, B, 64, 31);
    conv_enc_kernel<32,64><<<(B*64*14*14+255)/256, 256, 0, stream>>>(a1, conv2_w, conv2_b, a2, B, 31, 14);
    conv_enc_kernel<64,128><<<(B*128*6*6+255)/256, 256, 0, stream>>>(a2, conv3_w, conv3_b, a3, B, 14, 6);
    conv_enc_kernel<128,256><<<(B*256*2*2+255)/256, 256, 0, stream>>>(a3, conv4_w, conv4_b, flat, B, 6, 2);

    // fc1 -> z[:, :482]; action -> z[:, 482:512]
    {
        dim3 grid((482+31)/32, (B+31)/32);
        gemm_kernel<32,32,32,2,2,true,0,false><<<grid, 256, 0, stream>>>(flat, fc1_w, fc1_b, z, B, 482, 1024, 512, 1);
    }
    concat_action_kernel<<<(1500+63)/64, 64, 0, stream>>>(action, z);
    reward_kernel<<<1, 64, 0, stream>>>(z, fc5_w, fc5_b, out + 850*4096);

    // fc2 (leaky relu)
    {
        dim3 grid((1024+31)/32, (B+31)/32);
        gemm_kernel<32,32,32,2,2,true,2,false><<<grid, 256, 0, stream>>>(z, fc2_w, fc2_b, fc2o, B, 1024, 512, 1024, 1);
    }

    // LSTM, 17 steps
    dim3 ggrid((4096+31)/32, (B+31)/32);
    // step 0: g = fc2o @ w_ih^T + b_ih ; g += h0 @ w_hh^T + b_hh
    gemm_kernel<32,32,32,2,2,true,0,false><<<ggrid, 256, 0, stream>>>(fc2o, w_ih, b_ih, g, B, 4096, 1024, 4096, 1);
    gemm_kernel<32,32,32,2,2,true,0,true><<<ggrid, 256, 0, stream>>>(h0, w_hh, b_hh, g, B, 4096, 1024, 4096, 1);
    lstm_gates_kernel<<<200, 256, 0, stream>>>(g, c0, cbuf, hbuf, outs);
    for (int t = 1; t < 17; ++t) {
        gemm_kernel<32,32,32,2,2,true,0,false><<<ggrid, 256, 0, stream>>>(hbuf, wsum, bsum, g, B, 4096, 1024, 4096, 1);
        lstm_gates_kernel<<<200, 256, 0, stream>>>(g, cbuf, cbuf, hbuf, outs + t*51200);
    }

    // fcsd: hd = leaky(outs @ fcsd_w^T + fcsd_b)   [850,1024]
    {
        dim3 grid((1024+63)/64, (850+63)/64);
        gemm_kernel<64,64,32,4,4,true,2,false><<<grid, 256, 0, stream>>>(outs, fcsd_w, fcsd_b, hd, 850, 1024, 1024, 1024, 1);
    }
    // d1: 1x1 spatial input -> pure GEMM [850,1024]x[1024,3200], tanh
    {
        dim3 grid((3200+63)/64, (850+63)/64);
        gemm_kernel<64,64,32,4,4,false,1,false><<<grid, 256, 0, stream>>>(hd, d1_w, d1_b, y1, 850, 3200, 1024, 3200, 25);
    }
    // d2,d3,d4 direct transposed conv
    {
        int nx8 = (13+7)/8;
        int total = 850*64*13*nx8;
        deconv_kernel<128,64,5,1><<<(total+255)/256, 256, 0, stream>>>(y1, d2_w, d2_b, y2, 850, 5, 13);
    }
    {
        int nx8 = (30+7)/8;
        int total = 850*32*30*nx8;
        deconv_kernel<64,32,6,1><<<(total+255)/256, 256, 0, stream>>>(y2, d3_w, d3_b, y3, 850, 13, 30);
    }
    {
        int nx8 = (64+7)/8;
        int total = 850*1*64*nx8;
        deconv_kernel<32,1,6,0><<<(total+255)/256, 256, 0, stream>>>(y3, d4_w, d4_b, out, 850, 30, 64);
    }
    (void)in_sizes; (void)n_in; (void)out_size; (void)ws_size;
}

// Round 2
// 3687.255 us; speedup vs baseline: 2.2484x; 2.2484x over previous
//
#include <hip/hip_runtime.h>
#include <math.h>

#define DI __device__ __forceinline__

DI float sigm(float x){ return 1.0f/(1.0f+expf(-x)); }
DI float lrelu(float x){ return x > 0.f ? x : 0.01f*x; }

template<int ACT>
DI float act_apply(float v){
    if (ACT == 1) return tanhf(v);
    if (ACT == 2) return lrelu(v);
    return v;
}

// ---------------- encoder conv: stride 2, 4x4, tanh ----------------
template<int CIN, int COUT>
__global__ __launch_bounds__(256)
void conv_enc_kernel(const float* __restrict__ in, const float* __restrict__ w,
                     const float* __restrict__ bias, float* __restrict__ out,
                     int N, int H, int OH)
{
    int idx = blockIdx.x*256 + threadIdx.x;
    int total = N*COUT*OH*OH;
    if (idx >= total) return;
    int ox = idx % OH; int t = idx / OH;
    int oy = t % OH;   t /= OH;
    int o  = t % COUT; int n = t / COUT;
    float acc = bias[o];
    const float* wp = w + o*CIN*16;
    const float* ip = in + ((size_t)n*CIN)*H*H + (oy*2)*H + ox*2;
    for (int c = 0; c < CIN; ++c) {
        const float* ipc = ip + c*H*H;
        const float* wpc = wp + c*16;
        #pragma unroll
        for (int ky = 0; ky < 4; ++ky)
            #pragma unroll
            for (int kx = 0; kx < 4; ++kx)
                acc += ipc[ky*H + kx] * wpc[ky*4 + kx];
    }
    out[idx] = tanhf(acc);
}

// ---------------- tiled GEMM: C = act(A @ op(B) + bias), optional split-K ----
// A: [M,Kfull] row-major. BT ? B:[N,Kfull] : B:[Kfull,N]. TM=TN=4.
// blockIdx.z = K-split index; each split covers klen cols of K and writes
// C + z*partStride (raw partial, bias==nullptr) for later reduction.
template<int BM,int BN,int BK,bool BT,int ACT>
__global__ __launch_bounds__((BM/4)*(BN/4))
void gemm_kernel(const float* __restrict__ A, const float* __restrict__ Bm,
                 const float* __restrict__ bias, float* __restrict__ C,
                 int M, int N, int Kfull, int klen, int ldc, int bias_div,
                 long partStride)
{
    constexpr int TM = 4, TN = 4;
    constexpr int THREADS = (BM/TM)*(BN/TN);
    constexpr int LDA = BM + 4, LDB = BN + 4;
    __shared__ __align__(16) float As[BK][LDA];
    __shared__ __align__(16) float Bs[BK][LDB];
    int tid = threadIdx.x;
    int m0 = blockIdx.y * BM, n0 = blockIdx.x * BN;
    int koff = blockIdx.z * klen;
    C += (long)blockIdx.z * partStride;
    constexpr int NTX = BN/TN;
    int tx = tid % NTX, ty = tid / NTX;
    float acc[4][4];
    #pragma unroll
    for (int i=0;i<4;++i)
        #pragma unroll
        for (int j=0;j<4;++j) acc[i][j] = 0.f;

    for (int k0 = 0; k0 < klen; k0 += BK) {
        for (int e = tid; e < BM*BK; e += THREADS) {
            int k = e % BK, m = e / BK;
            As[k][m] = (m0+m < M) ? A[(size_t)(m0+m)*Kfull + koff + k0 + k] : 0.f;
        }
        if (BT) {
            for (int e = tid; e < BN*BK; e += THREADS) {
                int k = e % BK, n = e / BK;
                Bs[k][n] = (n0+n < N) ? Bm[(size_t)(n0+n)*Kfull + koff + k0 + k] : 0.f;
            }
        } else {
            for (int e = tid; e < BN*BK; e += THREADS) {
                int n = e % BN, k = e / BN;
                Bs[k][n] = (n0+n < N) ? Bm[(size_t)(koff + k0 + k)*N + n0+n] : 0.f;
            }
        }
        __syncthreads();
        #pragma unroll 8
        for (int k = 0; k < BK; ++k) {
            float4 a4 = *reinterpret_cast<const float4*>(&As[k][ty*4]);
            float4 b4 = *reinterpret_cast<const float4*>(&Bs[k][tx*4]);
            float av[4] = {a4.x, a4.y, a4.z, a4.w};
            float bv[4] = {b4.x, b4.y, b4.z, b4.w};
            #pragma unroll
            for (int i=0;i<4;++i)
                #pragma unroll
                for (int j=0;j<4;++j)
                    acc[i][j] += av[i]*bv[j];
        }
        __syncthreads();
    }
    #pragma unroll
    for (int i=0;i<4;++i) {
        int m = m0 + ty*4 + i;
        if (m >= M) continue;
        #pragma unroll
        for (int j=0;j<4;++j) {
            int n = n0 + tx*4 + j;
            if (n >= N) continue;
            float v = acc[i][j] + (bias ? bias[n / bias_div] : 0.f);
            C[(size_t)m*ldc + n] = act_apply<ACT>(v);
        }
    }
}

// ---------------- small helpers ----------------
__global__ __launch_bounds__(256)
void addvec_kernel(const float* __restrict__ a, const float* __restrict__ b,
                   float* __restrict__ o, int n)
{
    int i = blockIdx.x*256 + threadIdx.x;
    if (i < n) o[i] = a[i] + b[i];
}

__global__ __launch_bounds__(64)
void concat_action_kernel(const float* __restrict__ action, float* __restrict__ z)
{
    int i = blockIdx.x*64 + threadIdx.x;
    if (i < 50*30) { int b = i/30, k = i%30; z[b*512 + 482 + k] = action[i]; }
}

__global__ __launch_bounds__(64)
void reward_kernel(const float* __restrict__ z, const float* __restrict__ w,
                   const float* __restrict__ b, float* __restrict__ out)
{
    int bi = threadIdx.x;
    if (bi < 50) {
        float acc = b[0];
        for (int k = 0; k < 512; ++k) acc += z[bi*512 + k] * w[k];
        out[bi] = acc;
    }
}

// gates from 8 split-K partial buffers + combined bias
__global__ __launch_bounds__(256)
void lstm_gates8_kernel(const float* __restrict__ g8, const float* __restrict__ bsum,
                        const float* __restrict__ c_prev,
                        float* __restrict__ c_out, float* __restrict__ h_out,
                        float* __restrict__ outs_t)
{
    int idx = blockIdx.x*256 + threadIdx.x;
    if (idx >= 50*1024) return;
    int b = idx >> 10, j = idx & 1023;
    float s0 = bsum[j], s1 = bsum[1024+j], s2 = bsum[2048+j], s3 = bsum[3072+j];
    #pragma unroll
    for (int p = 0; p < 8; ++p) {
        const float* base = g8 + (size_t)p*204800 + b*4096 + j;
        s0 += base[0]; s1 += base[1024]; s2 += base[2048]; s3 += base[3072];
    }
    float cp = c_prev[idx];
    float c = sigm(s1)*cp + sigm(s0)*tanhf(s2);
    float h = sigm(s3)*tanhf(c);
    c_out[idx] = c; h_out[idx] = h; outs_t[idx] = h;
}

// ---------------- weight prep for parity-decomposed deconv ----------------
// wp[((py*2+px)*CIN + c)*COUT*12 + o*12 + j*4 + i] = w[c][o][py+2j][px+2i] (0 pad)
__global__ __launch_bounds__(256)
void wprep_kernel(const float* __restrict__ w, float* __restrict__ wp,
                  int CIN, int COUT, int KS)
{
    int idx = blockIdx.x*256 + threadIdx.x;
    int total = 4*CIN*COUT*12;
    if (idx >= total) return;
    int slot = idx % 12; int rem = idx / 12;
    int o = rem % COUT; rem /= COUT;
    int c = rem % CIN;  int pp = rem / CIN;
    int py = pp >> 1, px = pp & 1;
    int j = slot >> 2, i = slot & 3;
    int ky = py + 2*j, kx = px + 2*i;
    float v = 0.f;
    if (i < 3 && ky < KS && kx < KS)
        v = w[(((size_t)c*COUT + o)*KS + ky)*KS + kx];
    wp[idx] = v;
}

// ---------------- parity-decomposed transposed conv (stride 2) --------------
// One block per image n. Input slab zero-padded in LDS:
// slab[c][iy][0..1]=0, [2..HIN+1]=row, rest 0 (ROWP padded row, mult of 4).
// Task = (parity pp, o, ty[, txb]) computes a TW-wide strip of one output row.
// out[y=py+2ty][x=px+2(txb*TW+t)] = bias + sum_c sum_{j,i<3} in[c][ty-j][tx-i]*wp[..]
template<int CIN,int COUT,int HIN,int HOUT,int KS,int ACT,int CCHUNK,int ROWP,int TW,int TB>
__global__ __launch_bounds__(256)
void deconv2_kernel(const float* __restrict__ in, const float* __restrict__ wp,
                    const float* __restrict__ bias, float* __restrict__ out, int N)
{
    constexpr int NCHUNK = CIN / CCHUNK;
    constexpr int NTYMAX = (HOUT + 1) / 2;
    constexpr int TOTAL = 4 * TB * COUT * NTYMAX;
    __shared__ __align__(16) float slab[CCHUNK*HIN*ROWP];
    int n = blockIdx.x;
    int tid = threadIdx.x;
    const float* inb = in + (size_t)n*CIN*HIN*HIN;

    auto load_slab = [&](int c0){
        for (int r = tid; r < CCHUNK*HIN; r += 256) {
            int c = r / HIN, iy = r % HIN;
            const float* src = inb + ((size_t)(c0+c)*HIN + iy)*HIN;
            float* dst = slab + (c*HIN + iy)*ROWP;
            dst[0] = 0.f; dst[1] = 0.f;
            #pragma unroll
            for (int x2 = HIN+2; x2 < ROWP; ++x2) dst[x2] = 0.f;
            for (int x2 = 0; x2 < HIN; ++x2) dst[2+x2] = src[x2];
        }
    };

    if constexpr (NCHUNK == 1) {
        load_slab(0);
        __syncthreads();
        for (int task = tid; task < TOTAL; task += 256) {
            int ty = task % NTYMAX;
            int rem = task / NTYMAX;
            int o = rem % COUT; rem /= COUT;
            int txb = rem % TB; int pp = rem / TB;
            int py = pp >> 1, px = pp & 1;
            if (ty >= ((HOUT - py + 1) >> 1)) continue;
            int tx0 = txb * TW;
            float bv = bias[o];
            float acc[TW];
            #pragma unroll
            for (int t=0;t<TW;++t) acc[t] = bv;
            for (int c = 0; c < CIN; ++c) {
                const float4* wv4 = reinterpret_cast<const float4*>(
                    wp + (((size_t)pp*CIN + c)*COUT + o)*12);
                float4 w0 = wv4[0], w1 = wv4[1], w2 = wv4[2];
                const float* sc = slab + c*(HIN*ROWP);
                #pragma unroll
                for (int j = 0; j < 3; ++j) {
                    int iy = ty - j;
                    float r[TW+2];
                    if (iy >= 0 && iy < HIN) {
                        const float* srow = sc + iy*ROWP + tx0;
                        #pragma unroll
                        for (int u = 0; u+4 <= TW+2; u += 4) {
                            float4 q = *reinterpret_cast<const float4*>(srow + u);
                            r[u]=q.x; r[u+1]=q.y; r[u+2]=q.z; r[u+3]=q.w;
                        }
                        #pragma unroll
                        for (int u = ((TW+2)/4)*4; u < TW+2; ++u) r[u] = srow[u];
                    } else {
                        #pragma unroll
                        for (int u = 0; u < TW+2; ++u) r[u] = 0.f;
                    }
                    float wj0 = (j==0)?w0.x:(j==1)?w1.x:w2.x;
                    float wj1 = (j==0)?w0.y:(j==1)?w1.y:w2.y;
                    float wj2 = (j==0)?w0.z:(j==1)?w1.z:w2.z;
                    #pragma unroll
                    for (int t = 0; t < TW; ++t)
                        acc[t] += wj0*r[t+2] + wj1*r[t+1] + wj2*r[t];
                }
            }
            int ntx = (HOUT - px + 1) >> 1;
            int y = py + 2*ty;
            float* ob = out + (((size_t)n*COUT + o)*HOUT + y)*HOUT + px;
            #pragma unroll
            for (int t = 0; t < TW; ++t) {
                int txg = tx0 + t;
                if (txg < ntx) ob[2*txg] = act_apply<ACT>(acc[t]);
            }
        }
    } else {
        static_assert(TOTAL == 256 || NCHUNK == 1, "multi-chunk needs 1 task/thread");
        int task = tid;
        int ty = task % NTYMAX;
        int rem = task / NTYMAX;
        int o = rem % COUT; rem /= COUT;
        int txb = rem % TB; int pp = rem / TB;
        int py = pp >> 1, px = pp & 1;
        bool alive = (ty < ((HOUT - py + 1) >> 1));
        int tx0 = txb * TW;
        float bv = bias[o];
        float acc[TW];
        #pragma unroll
        for (int t=0;t<TW;++t) acc[t] = bv;
        for (int ch = 0; ch < NCHUNK; ++ch) {
            if (ch) __syncthreads();
            load_slab(ch*CCHUNK);
            __syncthreads();
            if (alive) {
                for (int c = 0; c < CCHUNK; ++c) {
                    int cg = ch*CCHUNK + c;
                    const float4* wv4 = reinterpret_cast<const float4*>(
                        wp + (((size_t)pp*CIN + cg)*COUT + o)*12);
                    float4 w0 = wv4[0], w1 = wv4[1], w2 = wv4[2];
                    const float* sc = slab + c*(HIN*ROWP);
                    #pragma unroll
                    for (int j = 0; j < 3; ++j) {
                        int iy = ty - j;
                        float r[TW+2];
                        if (iy >= 0 && iy < HIN) {
                            const float* srow = sc + iy*ROWP + tx0;
                            #pragma unroll
                            for (int u = 0; u+4 <= TW+2; u += 4) {
                                float4 q = *reinterpret_cast<const float4*>(srow + u);
                                r[u]=q.x; r[u+1]=q.y; r[u+2]=q.z; r[u+3]=q.w;
                            }
                            #pragma unroll
                            for (int u = ((TW+2)/4)*4; u < TW+2; ++u) r[u] = srow[u];
                        } else {
                            #pragma unroll
                            for (int u = 0; u < TW+2; ++u) r[u] = 0.f;
                        }
                        float wj0 = (j==0)?w0.x:(j==1)?w1.x:w2.x;
                        float wj1 = (j==0)?w0.y:(j==1)?w1.y:w2.y;
                        float wj2 = (j==0)?w0.z:(j==1)?w1.z:w2.z;
                        #pragma unroll
                        for (int t = 0; t < TW; ++t)
                            acc[t] += wj0*r[t+2] + wj1*r[t+1] + wj2*r[t];
                    }
                }
            }
        }
        if (alive) {
            int ntx = (HOUT - px + 1) >> 1;
            int y = py + 2*ty;
            float* ob = out + (((size_t)n*COUT + o)*HOUT + y)*HOUT + px;
            #pragma unroll
            for (int t = 0; t < TW; ++t) {
                int txg = tx0 + t;
                if (txg < ntx) ob[2*txg] = act_apply<ACT>(acc[t]);
            }
        }
    }
}

// ---------------- launch ----------------
extern "C" void kernel_launch(void* const* d_in, const int* in_sizes, int n_in,
                              void* d_out, int out_size, void* d_ws, size_t ws_size,
                              hipStream_t stream)
{
    const float* x       = (const float*)d_in[0];
    const float* action  = (const float*)d_in[1];
    const float* h0      = (const float*)d_in[2];
    const float* c0      = (const float*)d_in[3];
    const float* conv1_w = (const float*)d_in[4];  const float* conv1_b = (const float*)d_in[5];
    const float* conv2_w = (const float*)d_in[6];  const float* conv2_b = (const float*)d_in[7];
    const float* conv3_w = (const float*)d_in[8];  const float* conv3_b = (const float*)d_in[9];
    const float* conv4_w = (const float*)d_in[10]; const float* conv4_b = (const float*)d_in[11];
    const float* fc1_w   = (const float*)d_in[12]; const float* fc1_b   = (const float*)d_in[13];
    const float* fc2_w   = (const float*)d_in[14]; const float* fc2_b   = (const float*)d_in[15];
    const float* w_ih    = (const float*)d_in[16]; const float* w_hh    = (const float*)d_in[17];
    const float* b_ih    = (const float*)d_in[18]; const float* b_hh    = (const float*)d_in[19];
    const float* fcsd_w  = (const float*)d_in[20]; const float* fcsd_b  = (const float*)d_in[21];
    const float* d1_w    = (const float*)d_in[22]; const float* d1_b    = (const float*)d_in[23];
    const float* d2_w    = (const float*)d_in[24]; const float* d2_b    = (const float*)d_in[25];
    const float* d3_w    = (const float*)d_in[26]; const float* d3_b    = (const float*)d_in[27];
    const float* d4_w    = (const float*)d_in[28]; const float* d4_b    = (const float*)d_in[29];
    const float* fc5_w   = (const float*)d_in[30]; const float* fc5_b   = (const float*)d_in[31];
    float* out = (float*)d_out;
    float* ws  = (float*)d_ws;

    // workspace layout (floats)
    float* a1   = ws;                 // 1,537,600  [50,32,31,31]
    float* a2   = a1 + 1537600;       //   627,200  [50,64,14,14]
    float* a3   = a2 + 627200;        //   230,400  [50,128,6,6]
    float* flat = a3 + 230400;        //    51,200  [50,1024]
    float* z    = flat + 51200;       //    25,600  [50,512]
    float* fc2o = z + 25600;          //    51,200  [50,1024]
    float* hbuf = fc2o + 51200;       //    51,200
    float* cbuf = hbuf + 51200;       //    51,200
    float* outs = cbuf + 51200;       //   870,400  [17,50,1024]
    float* hd   = outs + 870400;      //   870,400  [850,1024]
    float* wsum = hd + 870400;        // 4,194,304
    float* bsum = wsum + 4194304;     //     4,096
    float* wp2  = bsum + 4096;        //   393,216  (4*128*64*12)
    float* wp3  = wp2 + 393216;       //    98,304  (4*64*32*12)
    float* wp4  = wp3 + 98304;        //     1,536  (4*32*1*12)
    float* y1   = wp4 + 1536;         // 2,720,000  [850,128,5,5]
    float* y2   = y1 + 2720000;       // 9,193,600  [850,64,13,13]
    float* y3   = y2 + 9193600;       // 24,480,000 [850,32,30,30]
    float* g8   = a1;                 // 8*204,800 = 1,638,400; aliases a1+a2 (dead by LSTM)

    const int B = 50;
    const long GP = 204800;  // per-part stride in g8

    // prep: wsum = w_ih + w_hh; bsum = b_ih + b_hh; parity-permuted deconv weights
    addvec_kernel<<<(4194304+255)/256, 256, 0, stream>>>(w_ih, w_hh, wsum, 4194304);
    addvec_kernel<<<(4096+255)/256, 256, 0, stream>>>(b_ih, b_hh, bsum, 4096);
    wprep_kernel<<<(4*128*64*12+255)/256, 256, 0, stream>>>(d2_w, wp2, 128, 64, 5);
    wprep_kernel<<<(4*64*32*12+255)/256, 256, 0, stream>>>(d3_w, wp3, 64, 32, 6);
    wprep_kernel<<<(4*32*1*12+255)/256, 256, 0, stream>>>(d4_w, wp4, 32, 1, 6);

    // encoder
    conv_enc_kernel<1,32><<<(B*32*31*31+255)/256, 256, 0, stream>>>(x, conv1_w, conv1_b, a1, B, 64, 31);
    conv_enc_kernel<32,64><<<(B*64*14*14+255)/256, 256, 0, stream>>>(a1, conv2_w, conv2_b, a2, B, 31, 14);
    conv_enc_kernel<64,128><<<(B*128*6*6+255)/256, 256, 0, stream>>>(a2, conv3_w, conv3_b, a3, B, 14, 6);
    conv_enc_kernel<128,256><<<(B*256*2*2+255)/256, 256, 0, stream>>>(a3, conv4_w, conv4_b, flat, B, 6, 2);

    // fc1 -> z[:, :482]; action -> z[:, 482:512]; reward head
    {
        dim3 grid((482+63)/64, (B+31)/32, 1);
        gemm_kernel<32,64,32,true,0><<<grid, 128, 0, stream>>>(flat, fc1_w, fc1_b, z, B, 482, 1024, 1024, 512, 1, 0);
    }
    concat_action_kernel<<<(1500+63)/64, 64, 0, stream>>>(action, z);
    reward_kernel<<<1, 64, 0, stream>>>(z, fc5_w, fc5_b, out + (size_t)850*4096);

    // fc2 (leaky relu)
    {
        dim3 grid((1024+63)/64, (B+31)/32, 1);
        gemm_kernel<32,64,32,true,2><<<grid, 128, 0, stream>>>(z, fc2_w, fc2_b, fc2o, B, 1024, 512, 512, 1024, 1, 0);
    }

    // LSTM, 17 steps. g8 holds 8 split-K partials; gates kernel reduces + bias.
    {
        dim3 grid0(64, 2, 4);
        gemm_kernel<32,64,32,true,0><<<grid0, 128, 0, stream>>>(fc2o, w_ih, nullptr, g8, B, 4096, 1024, 256, 4096, 1, GP);
        gemm_kernel<32,64,32,true,0><<<grid0, 128, 0, stream>>>(h0, w_hh, nullptr, g8 + 4*GP, B, 4096, 1024, 256, 4096, 1, GP);
        lstm_gates8_kernel<<<200, 256, 0, stream>>>(g8, bsum, c0, cbuf, hbuf, outs);
        dim3 gridt(64, 2, 8);
        for (int t = 1; t < 17; ++t) {
            gemm_kernel<32,64,32,true,0><<<gridt, 128, 0, stream>>>(hbuf, wsum, nullptr, g8, B, 4096, 1024, 128, 4096, 1, GP);
            lstm_gates8_kernel<<<200, 256, 0, stream>>>(g8, bsum, cbuf, cbuf, hbuf, outs + (size_t)t*51200);
        }
    }

    // fcsd: hd = leaky(outs @ fcsd_w^T + fcsd_b)   [850,1024]
    {
        dim3 grid((1024+63)/64, (850+63)/64, 1);
        gemm_kernel<64,64,32,true,2><<<grid, 256, 0, stream>>>(outs, fcsd_w, fcsd_b, hd, 850, 1024, 1024, 1024, 1024, 1, 0);
    }
    // d1: 1x1 spatial input -> pure GEMM [850,1024]x[1024,3200], tanh
    {
        dim3 grid((3200+63)/64, (850+63)/64, 1);
        gemm_kernel<64,64,32,false,1><<<grid, 256, 0, stream>>>(hd, d1_w, d1_b, y1, 850, 3200, 1024, 1024, 3200, 25, 0);
    }
    // d2,d3,d4: parity-decomposed deconvs, one block per image
    deconv2_kernel<128,64,5,13,5,1, 128,12,7,1><<<850, 256, 0, stream>>>(y1, wp2, d2_b, y2, 850);
    deconv2_kernel<64,32,13,30,6,1, 64,20,15,1><<<850, 256, 0, stream>>>(y2, wp3, d3_b, y3, 850);
    deconv2_kernel<32,1,30,64,6,0, 16,36,16,2><<<850, 256, 0, stream>>>(y3, wp4, d4_b, out, 850);

    (void)in_sizes; (void)n_in; (void)out_size; (void)ws_size;
}

// Round 3
// 3193.635 us; speedup vs baseline: 2.5959x; 1.1546x over previous
//
#include <hip/hip_runtime.h>
#include <math.h>

#define DI __device__ __forceinline__

DI float sigm(float x){ return 1.0f/(1.0f+expf(-x)); }
DI float lrelu(float x){ return x > 0.f ? x : 0.01f*x; }

template<int ACT>
DI float act_apply(float v){
    if (ACT == 1) return tanhf(v);
    if (ACT == 2) return lrelu(v);
    return v;
}

// ---------------- encoder conv: stride 2, 4x4, tanh ----------------
template<int CIN, int COUT>
__global__ __launch_bounds__(256)
void conv_enc_kernel(const float* __restrict__ in, const float* __restrict__ w,
                     const float* __restrict__ bias, float* __restrict__ out,
                     int N, int H, int OH)
{
    int idx = blockIdx.x*256 + threadIdx.x;
    int total = N*COUT*OH*OH;
    if (idx >= total) return;
    int ox = idx % OH; int t = idx / OH;
    int oy = t % OH;   t /= OH;
    int o  = t % COUT; int n = t / COUT;
    float acc = bias[o];
    const float* wp = w + o*CIN*16;
    const float* ip = in + ((size_t)n*CIN)*H*H + (oy*2)*H + ox*2;
    for (int c = 0; c < CIN; ++c) {
        const float* ipc = ip + c*H*H;
        const float* wpc = wp + c*16;
        #pragma unroll
        for (int ky = 0; ky < 4; ++ky)
            #pragma unroll
            for (int kx = 0; kx < 4; ++kx)
                acc += ipc[ky*H + kx] * wpc[ky*4 + kx];
    }
    out[idx] = tanhf(acc);
}

// ---------------- tiled GEMM: C = act(A @ op(B) + bias), optional split-K ----
template<int BM,int BN,int BK,bool BT,int ACT>
__global__ __launch_bounds__((BM/4)*(BN/4))
void gemm_kernel(const float* __restrict__ A, const float* __restrict__ Bm,
                 const float* __restrict__ bias, float* __restrict__ C,
                 int M, int N, int Kfull, int klen, int ldc, int bias_div,
                 long partStride)
{
    constexpr int TM = 4, TN = 4;
    constexpr int THREADS = (BM/TM)*(BN/TN);
    constexpr int LDA = BM + 4, LDB = BN + 4;
    __shared__ __align__(16) float As[BK][LDA];
    __shared__ __align__(16) float Bs[BK][LDB];
    int tid = threadIdx.x;
    int m0 = blockIdx.y * BM, n0 = blockIdx.x * BN;
    int koff = blockIdx.z * klen;
    C += (long)blockIdx.z * partStride;
    constexpr int NTX = BN/TN;
    int tx = tid % NTX, ty = tid / NTX;
    float acc[4][4];
    #pragma unroll
    for (int i=0;i<4;++i)
        #pragma unroll
        for (int j=0;j<4;++j) acc[i][j] = 0.f;

    for (int k0 = 0; k0 < klen; k0 += BK) {
        for (int e = tid; e < BM*BK; e += THREADS) {
            int k = e % BK, m = e / BK;
            As[k][m] = (m0+m < M) ? A[(size_t)(m0+m)*Kfull + koff + k0 + k] : 0.f;
        }
        if (BT) {
            for (int e = tid; e < BN*BK; e += THREADS) {
                int k = e % BK, n = e / BK;
                Bs[k][n] = (n0+n < N) ? Bm[(size_t)(n0+n)*Kfull + koff + k0 + k] : 0.f;
            }
        } else {
            for (int e = tid; e < BN*BK; e += THREADS) {
                int n = e % BN, k = e / BN;
                Bs[k][n] = (n0+n < N) ? Bm[(size_t)(koff + k0 + k)*N + n0+n] : 0.f;
            }
        }
        __syncthreads();
        #pragma unroll 8
        for (int k = 0; k < BK; ++k) {
            float4 a4 = *reinterpret_cast<const float4*>(&As[k][ty*4]);
            float4 b4 = *reinterpret_cast<const float4*>(&Bs[k][tx*4]);
            float av[4] = {a4.x, a4.y, a4.z, a4.w};
            float bv[4] = {b4.x, b4.y, b4.z, b4.w};
            #pragma unroll
            for (int i=0;i<4;++i)
                #pragma unroll
                for (int j=0;j<4;++j)
                    acc[i][j] += av[i]*bv[j];
        }
        __syncthreads();
    }
    #pragma unroll
    for (int i=0;i<4;++i) {
        int m = m0 + ty*4 + i;
        if (m >= M) continue;
        #pragma unroll
        for (int j=0;j<4;++j) {
            int n = n0 + tx*4 + j;
            if (n >= N) continue;
            float v = acc[i][j] + (bias ? bias[n / bias_div] : 0.f);
            C[(size_t)m*ldc + n] = act_apply<ACT>(v);
        }
    }
}

// ---------------- small helpers ----------------
__global__ __launch_bounds__(256)
void addvec_kernel(const float* __restrict__ a, const float* __restrict__ b,
                   float* __restrict__ o, int n)
{
    int i = blockIdx.x*256 + threadIdx.x;
    if (i < n) o[i] = a[i] + b[i];
}

__global__ __launch_bounds__(64)
void concat_action_kernel(const float* __restrict__ action, float* __restrict__ z)
{
    int i = blockIdx.x*64 + threadIdx.x;
    if (i < 50*30) { int b = i/30, k = i%30; z[b*512 + 482 + k] = action[i]; }
}

__global__ __launch_bounds__(64)
void reward_kernel(const float* __restrict__ z, const float* __restrict__ w,
                   const float* __restrict__ b, float* __restrict__ out)
{
    int bi = threadIdx.x;
    if (bi < 50) {
        float acc = b[0];
        for (int k = 0; k < 512; ++k) acc += z[bi*512 + k] * w[k];
        out[bi] = acc;
    }
}

// gates from 16 split-K partial buffers + combined bias
__global__ __launch_bounds__(256)
void lstm_gates16_kernel(const float* __restrict__ gp, const float* __restrict__ bsum,
                         const float* __restrict__ c_prev,
                         float* __restrict__ c_out, float* __restrict__ h_out,
                         float* __restrict__ outs_t)
{
    int idx = blockIdx.x*256 + threadIdx.x;
    if (idx >= 50*1024) return;
    int b = idx >> 10, j = idx & 1023;
    float s0 = bsum[j], s1 = bsum[1024+j], s2 = bsum[2048+j], s3 = bsum[3072+j];
    #pragma unroll
    for (int p = 0; p < 16; ++p) {
        const float* base = gp + (size_t)p*204800 + b*4096 + j;
        s0 += base[0]; s1 += base[1024]; s2 += base[2048]; s3 += base[3072];
    }
    float cp = c_prev[idx];
    float c = sigm(s1)*cp + sigm(s0)*tanhf(s2);
    float h = sigm(s3)*tanhf(c);
    c_out[idx] = c; h_out[idx] = h; outs_t[idx] = h;
}

// ---------------- weight prep for parity-decomposed deconv ----------------
// wp[((pp*CIN + c)*COUT + o)*12 + j*4 + i] = w[c][o][py+2j][px+2i] (0 pad), pp=py*2+px
__global__ __launch_bounds__(256)
void wprep_kernel(const float* __restrict__ w, float* __restrict__ wp,
                  int CIN, int COUT, int KS)
{
    int idx = blockIdx.x*256 + threadIdx.x;
    int total = 4*CIN*COUT*12;
    if (idx >= total) return;
    int slot = idx % 12; int rem = idx / 12;
    int o = rem % COUT; rem /= COUT;
    int c = rem % CIN;  int pp = rem / CIN;
    int py = pp >> 1, px = pp & 1;
    int j = slot >> 2, i = slot & 3;
    int ky = py + 2*j, kx = px + 2*i;
    float v = 0.f;
    if (i < 3 && ky < KS && kx < KS)
        v = w[(((size_t)c*COUT + o)*KS + ky)*KS + kx];
    wp[idx] = v;
}

// ---------------- parity-MERGED transposed conv (stride 2) ------------------
// One block per image n. Task = (o, v [, txb]) computes a 2-row (y=2v,2v+1)
// by 2*TWU-wide contiguous output patch: all 4 parities share the same input
// rows iy=v-j and columns ix=u-i. Slab rows are zero-padded: [0,1]=0,
// [2..HIN+1]=data, rest 0.
template<int CIN,int COUT,int HIN,int HOUT,int ACT,int CCHUNK,int ROWP,int TWU,int TB>
__global__ __launch_bounds__(256)
void deconv3_kernel(const float* __restrict__ in, const float* __restrict__ wp,
                    const float* __restrict__ bias, float* __restrict__ out, int N)
{
    constexpr int NCHUNK = CIN / CCHUNK;
    constexpr int NV = (HOUT + 1) / 2;
    constexpr int NTASK = COUT * NV * TB;
    constexpr int NR4 = (TWU + 2 + 3) / 4;           // float4s per row read
    static_assert(NCHUNK == 1 || NTASK <= 256, "multi-chunk needs <=1 task/thread");
    __shared__ __align__(16) float slab[CCHUNK*HIN*ROWP];
    int n = blockIdx.x;
    int tid = threadIdx.x;
    const float* inb = in + (size_t)n*CIN*HIN*HIN;
    const size_t PPSTR = (size_t)CIN*COUT*12;

    auto load_slab = [&](int c0){
        for (int r = tid; r < CCHUNK*HIN; r += 256) {
            int c = r / HIN, iy = r % HIN;
            const float* src = inb + ((size_t)(c0+c)*HIN + iy)*HIN;
            float* dst = slab + (c*HIN + iy)*ROWP;
            dst[0] = 0.f; dst[1] = 0.f;
            #pragma unroll
            for (int x2 = HIN+2; x2 < ROWP; ++x2) dst[x2] = 0.f;
            for (int x2 = 0; x2 < HIN; ++x2) dst[2+x2] = src[x2];
        }
    };

    // inner: accumulate one channel's contribution for task (o,v,u0)
    auto chan_acc = [&](int cSlab, int cGlob, int o, int v, int u0,
                        float acc[2][2][TWU]) {
        const float* wbase = wp + ((size_t)cGlob*COUT + o)*12;
        const float* sc = slab + cSlab*(HIN*ROWP);
        #pragma unroll
        for (int jj = 0; jj < 3; ++jj) {
            int iy = v - jj;
            float r[NR4*4];
            if (iy >= 0 && iy < HIN) {
                const float* srow = sc + iy*ROWP + u0;
                #pragma unroll
                for (int q = 0; q < NR4; ++q) {
                    float4 f = *reinterpret_cast<const float4*>(srow + q*4);
                    r[q*4]=f.x; r[q*4+1]=f.y; r[q*4+2]=f.z; r[q*4+3]=f.w;
                }
            } else {
                #pragma unroll
                for (int q = 0; q < NR4*4; ++q) r[q] = 0.f;
            }
            #pragma unroll
            for (int pp = 0; pp < 4; ++pp) {
                float4 w4 = *reinterpret_cast<const float4*>(wbase + pp*PPSTR + jj*4);
                int py = pp >> 1, px = pp & 1;
                #pragma unroll
                for (int t = 0; t < TWU; ++t)
                    acc[py][px][t] += w4.x*r[t+2] + w4.y*r[t+1] + w4.z*r[t];
            }
        }
    };

    auto store_task = [&](int o, int v, int u0, float acc[2][2][TWU]) {
        float bv = bias[o];
        #pragma unroll
        for (int py = 0; py < 2; ++py) {
            int y = py + 2*v;
            if (y >= HOUT) continue;
            float* ob = out + (((size_t)n*COUT + o)*HOUT + y)*HOUT + 2*u0;
            #pragma unroll
            for (int t = 0; t < TWU; ++t) {
                int x0 = 2*(u0+t);
                if (x0 + 1 < HOUT) {
                    float2 q;
                    q.x = act_apply<ACT>(acc[py][0][t] + bv);
                    q.y = act_apply<ACT>(acc[py][1][t] + bv);
                    *reinterpret_cast<float2*>(ob + 2*t) = q;
                } else if (x0 < HOUT) {
                    ob[2*t] = act_apply<ACT>(acc[py][0][t] + bv);
                }
            }
        }
    };

    if constexpr (NCHUNK == 1) {
        load_slab(0);
        __syncthreads();
        for (int task = tid; task < NTASK; task += 256) {
            int v = task % NV; int rem = task / NV;
            int o = rem % COUT; int txb = rem / COUT;
            int u0 = txb * TWU;
            float acc[2][2][TWU];
            #pragma unroll
            for (int a=0;a<2;++a)
                #pragma unroll
                for (int b=0;b<2;++b)
                    #pragma unroll
                    for (int t=0;t<TWU;++t) acc[a][b][t] = 0.f;
            for (int c = 0; c < CIN; ++c)
                chan_acc(c, c, o, v, u0, acc);
            store_task(o, v, u0, acc);
        }
    } else {
        int task = tid;
        int v = task % NV; int rem = task / NV;
        int o = rem % COUT; int txb = rem / COUT;
        int u0 = txb * TWU;
        bool alive = (task < NTASK);
        float acc[2][2][TWU];
        #pragma unroll
        for (int a=0;a<2;++a)
            #pragma unroll
            for (int b=0;b<2;++b)
                #pragma unroll
                for (int t=0;t<TWU;++t) acc[a][b][t] = 0.f;
        for (int ch = 0; ch < NCHUNK; ++ch) {
            if (ch) __syncthreads();
            load_slab(ch*CCHUNK);
            __syncthreads();
            if (alive)
                for (int c = 0; c < CCHUNK; ++c)
                    chan_acc(c, ch*CCHUNK + c, o, v, u0, acc);
        }
        if (alive) store_task(o, v, u0, acc);
    }
}

// ---------------- launch ----------------
extern "C" void kernel_launch(void* const* d_in, const int* in_sizes, int n_in,
                              void* d_out, int out_size, void* d_ws, size_t ws_size,
                              hipStream_t stream)
{
    const float* x       = (const float*)d_in[0];
    const float* action  = (const float*)d_in[1];
    const float* h0      = (const float*)d_in[2];
    const float* c0      = (const float*)d_in[3];
    const float* conv1_w = (const float*)d_in[4];  const float* conv1_b = (const float*)d_in[5];
    const float* conv2_w = (const float*)d_in[6];  const float* conv2_b = (const float*)d_in[7];
    const float* conv3_w = (const float*)d_in[8];  const float* conv3_b = (const float*)d_in[9];
    const float* conv4_w = (const float*)d_in[10]; const float* conv4_b = (const float*)d_in[11];
    const float* fc1_w   = (const float*)d_in[12]; const float* fc1_b   = (const float*)d_in[13];
    const float* fc2_w   = (const float*)d_in[14]; const float* fc2_b   = (const float*)d_in[15];
    const float* w_ih    = (const float*)d_in[16]; const float* w_hh    = (const float*)d_in[17];
    const float* b_ih    = (const float*)d_in[18]; const float* b_hh    = (const float*)d_in[19];
    const float* fcsd_w  = (const float*)d_in[20]; const float* fcsd_b  = (const float*)d_in[21];
    const float* d1_w    = (const float*)d_in[22]; const float* d1_b    = (const float*)d_in[23];
    const float* d2_w    = (const float*)d_in[24]; const float* d2_b    = (const float*)d_in[25];
    const float* d3_w    = (const float*)d_in[26]; const float* d3_b    = (const float*)d_in[27];
    const float* d4_w    = (const float*)d_in[28]; const float* d4_b    = (const float*)d_in[29];
    const float* fc5_w   = (const float*)d_in[30]; const float* fc5_b   = (const float*)d_in[31];
    float* out = (float*)d_out;
    float* ws  = (float*)d_ws;

    // workspace layout (floats)
    float* a1   = ws;                 // 1,537,600  [50,32,31,31]
    float* a2   = a1 + 1537600;       //   627,200  [50,64,14,14]
    float* a3   = a2 + 627200;        //   230,400  [50,128,6,6]
    float* flat = a3 + 230400;        //    51,200  [50,1024]
    float* z    = flat + 51200;       //    25,600  [50,512]
    float* fc2o = z + 25600;          //    51,200  [50,1024]
    float* hbuf = fc2o + 51200;       //    51,200
    float* cbuf = hbuf + 51200;       //    51,200
    float* outs = cbuf + 51200;       //   870,400  [17,50,1024]
    float* hd   = outs + 870400;      //   870,400  [850,1024]
    float* wsum = hd + 870400;        // 4,194,304
    float* bsum = wsum + 4194304;     //     4,096
    float* wp2  = bsum + 4096;        //   393,216
    float* wp3  = wp2 + 393216;       //    98,304
    float* wp4  = wp3 + 98304;        //     1,536
    float* y1   = wp4 + 1536;         // 2,720,000  [850,128,5,5]
    float* y2   = y1 + 2720000;       // 9,193,600  [850,64,13,13]
    float* y3   = y2 + 9193600;       // 24,480,000 [850,32,30,30]
    float* g16  = y1;                 // 16*204,800 = 3.28M floats; y1+y2 dead during LSTM

    const int B = 50;
    const long GP = 204800;  // per-part stride in g16

    // prep
    addvec_kernel<<<(4194304+255)/256, 256, 0, stream>>>(w_ih, w_hh, wsum, 4194304);
    addvec_kernel<<<(4096+255)/256, 256, 0, stream>>>(b_ih, b_hh, bsum, 4096);
    wprep_kernel<<<(4*128*64*12+255)/256, 256, 0, stream>>>(d2_w, wp2, 128, 64, 5);
    wprep_kernel<<<(4*64*32*12+255)/256, 256, 0, stream>>>(d3_w, wp3, 64, 32, 6);
    wprep_kernel<<<(4*32*1*12+255)/256, 256, 0, stream>>>(d4_w, wp4, 32, 1, 6);

    // encoder
    conv_enc_kernel<1,32><<<(B*32*31*31+255)/256, 256, 0, stream>>>(x, conv1_w, conv1_b, a1, B, 64, 31);
    conv_enc_kernel<32,64><<<(B*64*14*14+255)/256, 256, 0, stream>>>(a1, conv2_w, conv2_b, a2, B, 31, 14);
    conv_enc_kernel<64,128><<<(B*128*6*6+255)/256, 256, 0, stream>>>(a2, conv3_w, conv3_b, a3, B, 14, 6);
    conv_enc_kernel<128,256><<<(B*256*2*2+255)/256, 256, 0, stream>>>(a3, conv4_w, conv4_b, flat, B, 6, 2);

    // fc1 -> z[:, :482]; action -> z[:, 482:512]; reward head
    {
        dim3 grid((482+63)/64, (B+31)/32, 1);
        gemm_kernel<32,64,32,true,0><<<grid, 128, 0, stream>>>(flat, fc1_w, fc1_b, z, B, 482, 1024, 1024, 512, 1, 0);
    }
    concat_action_kernel<<<(1500+63)/64, 64, 0, stream>>>(action, z);
    reward_kernel<<<1, 64, 0, stream>>>(z, fc5_w, fc5_b, out + (size_t)850*4096);

    // fc2 (leaky relu)
    {
        dim3 grid((1024+63)/64, (B+31)/32, 1);
        gemm_kernel<32,64,32,true,2><<<grid, 128, 0, stream>>>(z, fc2_w, fc2_b, fc2o, B, 1024, 512, 512, 1024, 1, 0);
    }

    // LSTM, 17 steps, split-K 16 partials in g16 (dead y1/y2 region)
    {
        dim3 grid0(64, 2, 8);
        gemm_kernel<32,64,32,true,0><<<grid0, 128, 0, stream>>>(fc2o, w_ih, nullptr, g16, B, 4096, 1024, 128, 4096, 1, GP);
        gemm_kernel<32,64,32,true,0><<<grid0, 128, 0, stream>>>(h0, w_hh, nullptr, g16 + 8*GP, B, 4096, 1024, 128, 4096, 1, GP);
        lstm_gates16_kernel<<<200, 256, 0, stream>>>(g16, bsum, c0, cbuf, hbuf, outs);
        dim3 gridt(64, 2, 16);
        for (int t = 1; t < 17; ++t) {
            gemm_kernel<32,64,32,true,0><<<gridt, 128, 0, stream>>>(hbuf, wsum, nullptr, g16, B, 4096, 1024, 64, 4096, 1, GP);
            lstm_gates16_kernel<<<200, 256, 0, stream>>>(g16, bsum, cbuf, cbuf, hbuf, outs + (size_t)t*51200);
        }
    }

    // fcsd: hd = leaky(outs @ fcsd_w^T + fcsd_b)   [850,1024]
    {
        dim3 grid((1024+63)/64, (850+63)/64, 1);
        gemm_kernel<64,64,32,true,2><<<grid, 256, 0, stream>>>(outs, fcsd_w, fcsd_b, hd, 850, 1024, 1024, 1024, 1024, 1, 0);
    }
    // d1: 1x1 spatial input -> pure GEMM [850,1024]x[1024,3200], tanh
    {
        dim3 grid((3200+63)/64, (850+63)/64, 1);
        gemm_kernel<64,64,32,false,1><<<grid, 256, 0, stream>>>(hd, d1_w, d1_b, y1, 850, 3200, 1024, 1024, 3200, 25, 0);
    }
    // d2,d3,d4: parity-merged deconvs, one block per image
    deconv3_kernel<128,64,5,13,1, 128,12,7,1><<<850, 256, 0, stream>>>(y1, wp2, d2_b, y2, 850);
    deconv3_kernel<64,32,13,30,1, 64,20,15,1><<<850, 256, 0, stream>>>(y2, wp3, d3_b, y3, 850);
    deconv3_kernel<32,1,30,64,0, 16,36,4,8><<<850, 256, 0, stream>>>(y3, wp4, d4_b, out, 850);

    (void)in_sizes; (void)n_in; (void)out_size; (void)ws_size;
}

// Round 4
// 3034.675 us; speedup vs baseline: 2.7319x; 1.0524x over previous
//
#include <hip/hip_runtime.h>
#include <math.h>

#define DI __device__ __forceinline__

DI float sigm(float x){ return 1.0f/(1.0f+expf(-x)); }
DI float lrelu(float x){ return x > 0.f ? x : 0.01f*x; }

template<int ACT>
DI float act_apply(float v){
    if (ACT == 1) return tanhf(v);
    if (ACT == 2) return lrelu(v);
    return v;
}

// ---------------- encoder conv: stride 2, 4x4, tanh ----------------
template<int CIN, int COUT>
__global__ __launch_bounds__(256)
void conv_enc_kernel(const float* __restrict__ in, const float* __restrict__ w,
                     const float* __restrict__ bias, float* __restrict__ out,
                     int N, int H, int OH)
{
    int idx = blockIdx.x*256 + threadIdx.x;
    int total = N*COUT*OH*OH;
    if (idx >= total) return;
    int ox = idx % OH; int t = idx / OH;
    int oy = t % OH;   t /= OH;
    int o  = t % COUT; int n = t / COUT;
    float acc = bias[o];
    const float* wp = w + o*CIN*16;
    const float* ip = in + ((size_t)n*CIN)*H*H + (oy*2)*H + ox*2;
    for (int c = 0; c < CIN; ++c) {
        const float* ipc = ip + c*H*H;
        const float* wpc = wp + c*16;
        #pragma unroll
        for (int ky = 0; ky < 4; ++ky)
            #pragma unroll
            for (int kx = 0; kx < 4; ++kx)
                acc = fmaf(ipc[ky*H + kx], wpc[ky*4 + kx], acc);
    }
    out[idx] = tanhf(acc);
}

// ---------------- tiled GEMM: C = act(A @ op(B) + bias), optional split-K ----
template<int BM,int BN,int BK,bool BT,int ACT>
__global__ __launch_bounds__((BM/4)*(BN/4))
void gemm_kernel(const float* __restrict__ A, const float* __restrict__ Bm,
                 const float* __restrict__ bias, float* __restrict__ C,
                 int M, int N, int Kfull, int klen, int ldc, int bias_div,
                 long partStride)
{
    constexpr int TM = 4, TN = 4;
    constexpr int THREADS = (BM/TM)*(BN/TN);
    constexpr int LDA = BM + 4, LDB = BN + 4;
    __shared__ __align__(16) float As[BK][LDA];
    __shared__ __align__(16) float Bs[BK][LDB];
    int tid = threadIdx.x;
    int m0 = blockIdx.y * BM, n0 = blockIdx.x * BN;
    int koff = blockIdx.z * klen;
    C += (long)blockIdx.z * partStride;
    constexpr int NTX = BN/TN;
    int tx = tid % NTX, ty = tid / NTX;
    float acc[4][4];
    #pragma unroll
    for (int i=0;i<4;++i)
        #pragma unroll
        for (int j=0;j<4;++j) acc[i][j] = 0.f;

    for (int k0 = 0; k0 < klen; k0 += BK) {
        for (int e = tid; e < BM*BK; e += THREADS) {
            int k = e % BK, m = e / BK;
            As[k][m] = (m0+m < M) ? A[(size_t)(m0+m)*Kfull + koff + k0 + k] : 0.f;
        }
        if (BT) {
            for (int e = tid; e < BN*BK; e += THREADS) {
                int k = e % BK, n = e / BK;
                Bs[k][n] = (n0+n < N) ? Bm[(size_t)(n0+n)*Kfull + koff + k0 + k] : 0.f;
            }
        } else {
            for (int e = tid; e < BN*BK; e += THREADS) {
                int n = e % BN, k = e / BN;
                Bs[k][n] = (n0+n < N) ? Bm[(size_t)(koff + k0 + k)*N + n0+n] : 0.f;
            }
        }
        __syncthreads();
        #pragma unroll 8
        for (int k = 0; k < BK; ++k) {
            float4 a4 = *reinterpret_cast<const float4*>(&As[k][ty*4]);
            float4 b4 = *reinterpret_cast<const float4*>(&Bs[k][tx*4]);
            float av[4] = {a4.x, a4.y, a4.z, a4.w};
            float bv[4] = {b4.x, b4.y, b4.z, b4.w};
            #pragma unroll
            for (int i=0;i<4;++i)
                #pragma unroll
                for (int j=0;j<4;++j)
                    acc[i][j] = fmaf(av[i], bv[j], acc[i][j]);
        }
        __syncthreads();
    }
    #pragma unroll
    for (int i=0;i<4;++i) {
        int m = m0 + ty*4 + i;
        if (m >= M) continue;
        #pragma unroll
        for (int j=0;j<4;++j) {
            int n = n0 + tx*4 + j;
            if (n >= N) continue;
            float v = acc[i][j] + (bias ? bias[n / bias_div] : 0.f);
            C[(size_t)m*ldc + n] = act_apply<ACT>(v);
        }
    }
}

// ---------------- small helpers ----------------
__global__ __launch_bounds__(256)
void addvec_kernel(const float* __restrict__ a, const float* __restrict__ b,
                   float* __restrict__ o, int n)
{
    int i = blockIdx.x*256 + threadIdx.x;
    if (i < n) o[i] = a[i] + b[i];
}

__global__ __launch_bounds__(64)
void concat_action_kernel(const float* __restrict__ action, float* __restrict__ z)
{
    int i = blockIdx.x*64 + threadIdx.x;
    if (i < 50*30) { int b = i/30, k = i%30; z[b*512 + 482 + k] = action[i]; }
}

__global__ __launch_bounds__(64)
void reward_kernel(const float* __restrict__ z, const float* __restrict__ w,
                   const float* __restrict__ b, float* __restrict__ out)
{
    int bi = threadIdx.x;
    if (bi < 50) {
        float acc = b[0];
        for (int k = 0; k < 512; ++k) acc = fmaf(z[bi*512 + k], w[k], acc);
        out[bi] = acc;
    }
}

// gates from 16 split-K partial buffers + combined bias
__global__ __launch_bounds__(256)
void lstm_gates16_kernel(const float* __restrict__ gp, const float* __restrict__ bsum,
                         const float* __restrict__ c_prev,
                         float* __restrict__ c_out, float* __restrict__ h_out,
                         float* __restrict__ outs_t)
{
    int idx = blockIdx.x*256 + threadIdx.x;
    if (idx >= 50*1024) return;
    int b = idx >> 10, j = idx & 1023;
    float s0 = bsum[j], s1 = bsum[1024+j], s2 = bsum[2048+j], s3 = bsum[3072+j];
    #pragma unroll
    for (int p = 0; p < 16; ++p) {
        const float* base = gp + (size_t)p*204800 + b*4096 + j;
        s0 += base[0]; s1 += base[1024]; s2 += base[2048]; s3 += base[3072];
    }
    float cp = c_prev[idx];
    float c = sigm(s1)*cp + sigm(s0)*tanhf(s2);
    float h = sigm(s3)*tanhf(c);
    c_out[idx] = c; h_out[idx] = h; outs_t[idx] = h;
}

// ---------------- weight prep for parity-decomposed deconv ----------------
// wp[((pp*CIN + c)*COUT + o)*12 + j*4 + i] = w[c][o][py+2j][px+2i] (0 pad), pp=py*2+px
__global__ __launch_bounds__(256)
void wprep_kernel(const float* __restrict__ w, float* __restrict__ wp,
                  int CIN, int COUT, int KS)
{
    int idx = blockIdx.x*256 + threadIdx.x;
    int total = 4*CIN*COUT*12;
    if (idx >= total) return;
    int slot = idx % 12; int rem = idx / 12;
    int o = rem % COUT; rem /= COUT;
    int c = rem % CIN;  int pp = rem / CIN;
    int py = pp >> 1, px = pp & 1;
    int j = slot >> 2, i = slot & 3;
    int ky = py + 2*j, kx = px + 2*i;
    float v = 0.f;
    if (i < 3 && ky < KS && kx < KS)
        v = w[(((size_t)c*COUT + o)*KS + ky)*KS + kx];
    wp[idx] = v;
}

// ---------------- parity-merged transposed conv, v-split blocks -------------
// Block = (n, seg). Segment covers v in [v0,v1), slab holds input rows
// [r0..r1] zero-padded left/right by 2. Task = (vi, o, tb): computes, for
// VPER v's (v = v0+vi+q*NVB), a 2-row x 2*TWU output patch at u0=tb*TWU.
// MWAVES: __launch_bounds__ min-waves-per-EU (VGPR cap).
template<int CIN,int COUT,int HIN,int HOUT,int ACT,int VSPLIT,int ROWP,int TWU,
         int VPER,int TB,int MWAVES>
__global__ __launch_bounds__(256, MWAVES)
void deconv4_kernel(const float* __restrict__ in, const float* __restrict__ wp,
                    const float* __restrict__ bias, float* __restrict__ out)
{
    constexpr int NV = (HOUT + 1) / 2;
    constexpr int NVSEG = (NV + VSPLIT - 1) / VSPLIT;
    constexpr int NVB = (NVSEG + VPER - 1) / VPER;
    constexpr int ROWS_MAX = NVSEG + 2;
    constexpr int NR4 = (TWU + 2 + 3) / 4;
    constexpr int RLEN = (TWU == 1) ? 4 : NR4*4;
    static_assert(NVB * COUT * TB <= 256, "tasks must fit one per thread");
    __shared__ __align__(16) float slab[CIN*ROWS_MAX*ROWP];

    int n   = blockIdx.x / VSPLIT;
    int seg = blockIdx.x % VSPLIT;
    int v0 = seg * NVSEG;
    int v1 = (v0 + NVSEG < NV) ? v0 + NVSEG : NV;
    int r0 = (v0 - 2 > 0) ? v0 - 2 : 0;
    int r1m = (v1 - 1 < HIN - 1) ? v1 - 1 : HIN - 1;
    int nrows = r1m - r0 + 1;
    int tid = threadIdx.x;
    const float* inb = in + (size_t)n*CIN*HIN*HIN;
    const size_t PPSTR = (size_t)CIN*COUT*12;

    // stage slab
    for (int e = tid; e < CIN*ROWS_MAX; e += 256) {
        int c = e / ROWS_MAX, ri = e % ROWS_MAX;
        if (ri < nrows) {
            const float* src = inb + ((size_t)c*HIN + r0 + ri)*HIN;
            float* dst = slab + (c*ROWS_MAX + ri)*ROWP;
            dst[0] = 0.f; dst[1] = 0.f;
            #pragma unroll
            for (int x2 = HIN+2; x2 < ROWP; ++x2) dst[x2] = 0.f;
            for (int x2 = 0; x2 < HIN; ++x2) dst[2+x2] = src[x2];
        }
    }
    __syncthreads();

    int task = tid;
    int vi = task % NVB; int rem = task / NVB;
    int o = rem % COUT;  int tb = rem / COUT;
    int u0 = tb * TWU;
    bool anyv = false;
    int vg[VPER];
    #pragma unroll
    for (int q = 0; q < VPER; ++q) {
        vg[q] = v0 + vi + q*NVB;
        if (vg[q] < v1) anyv = true;
    }
    if (tb >= TB) anyv = false;

    float acc[VPER][2][2][TWU];
    #pragma unroll
    for (int q=0;q<VPER;++q)
        #pragma unroll
        for (int a=0;a<2;++a)
            #pragma unroll
            for (int b=0;b<2;++b)
                #pragma unroll
                for (int t=0;t<TWU;++t) acc[q][a][b][t] = 0.f;

    if (anyv) {
        const float* wb0 = wp + ((size_t)0*COUT + o)*12;
        for (int c = 0; c < CIN; ++c) {
            const float* wbase = wb0 + (size_t)c*COUT*12;
            const float* sc = slab + c*(ROWS_MAX*ROWP);
            #pragma unroll
            for (int jj = 0; jj < 3; ++jj) {
                float r[VPER][RLEN];
                #pragma unroll
                for (int q = 0; q < VPER; ++q) {
                    int iy = vg[q] - jj;
                    if (iy >= 0 && iy < HIN) {
                        const float* srow = sc + (iy - r0)*ROWP + u0;
                        if constexpr (TWU == 1) {
                            r[q][0] = srow[0]; r[q][1] = srow[1]; r[q][2] = srow[2];
                        } else {
                            #pragma unroll
                            for (int p4 = 0; p4 < NR4; ++p4) {
                                float4 f = *reinterpret_cast<const float4*>(srow + p4*4);
                                r[q][p4*4]=f.x; r[q][p4*4+1]=f.y; r[q][p4*4+2]=f.z; r[q][p4*4+3]=f.w;
                            }
                        }
                    } else {
                        #pragma unroll
                        for (int p4 = 0; p4 < RLEN; ++p4) r[q][p4] = 0.f;
                    }
                }
                #pragma unroll
                for (int pp = 0; pp < 4; ++pp) {
                    float4 w4 = *reinterpret_cast<const float4*>(wbase + pp*PPSTR + jj*4);
                    int py = pp >> 1, px = pp & 1;
                    #pragma unroll
                    for (int q = 0; q < VPER; ++q)
                        #pragma unroll
                        for (int t = 0; t < TWU; ++t)
                            acc[q][py][px][t] =
                                fmaf(w4.x, r[q][t+2],
                                fmaf(w4.y, r[q][t+1],
                                fmaf(w4.z, r[q][t], acc[q][py][px][t])));
                }
            }
        }
        // store
        float bv = bias[o];
        #pragma unroll
        for (int q = 0; q < VPER; ++q) {
            if (vg[q] >= v1) continue;
            #pragma unroll
            for (int py = 0; py < 2; ++py) {
                int y = py + 2*vg[q];
                if (y >= HOUT) continue;
                float* ob = out + (((size_t)n*COUT + o)*HOUT + y)*HOUT;
                #pragma unroll
                for (int t = 0; t < TWU; ++t) {
                    int x0 = 2*(u0+t);
                    if (x0 + 1 < HOUT) {
                        float2 qv;
                        qv.x = act_apply<ACT>(acc[q][py][0][t] + bv);
                        qv.y = act_apply<ACT>(acc[q][py][1][t] + bv);
                        *reinterpret_cast<float2*>(ob + x0) = qv;
                    } else if (x0 < HOUT) {
                        ob[x0] = act_apply<ACT>(acc[q][py][0][t] + bv);
                    }
                }
            }
        }
    }
}

// ---------------- launch ----------------
extern "C" void kernel_launch(void* const* d_in, const int* in_sizes, int n_in,
                              void* d_out, int out_size, void* d_ws, size_t ws_size,
                              hipStream_t stream)
{
    const float* x       = (const float*)d_in[0];
    const float* action  = (const float*)d_in[1];
    const float* h0      = (const float*)d_in[2];
    const float* c0      = (const float*)d_in[3];
    const float* conv1_w = (const float*)d_in[4];  const float* conv1_b = (const float*)d_in[5];
    const float* conv2_w = (const float*)d_in[6];  const float* conv2_b = (const float*)d_in[7];
    const float* conv3_w = (const float*)d_in[8];  const float* conv3_b = (const float*)d_in[9];
    const float* conv4_w = (const float*)d_in[10]; const float* conv4_b = (const float*)d_in[11];
    const float* fc1_w   = (const float*)d_in[12]; const float* fc1_b   = (const float*)d_in[13];
    const float* fc2_w   = (const float*)d_in[14]; const float* fc2_b   = (const float*)d_in[15];
    const float* w_ih    = (const float*)d_in[16]; const float* w_hh    = (const float*)d_in[17];
    const float* b_ih    = (const float*)d_in[18]; const float* b_hh    = (const float*)d_in[19];
    const float* fcsd_w  = (const float*)d_in[20]; const float* fcsd_b  = (const float*)d_in[21];
    const float* d1_w    = (const float*)d_in[22]; const float* d1_b    = (const float*)d_in[23];
    const float* d2_w    = (const float*)d_in[24]; const float* d2_b    = (const float*)d_in[25];
    const float* d3_w    = (const float*)d_in[26]; const float* d3_b    = (const float*)d_in[27];
    const float* d4_w    = (const float*)d_in[28]; const float* d4_b    = (const float*)d_in[29];
    const float* fc5_w   = (const float*)d_in[30]; const float* fc5_b   = (const float*)d_in[31];
    float* out = (float*)d_out;
    float* ws  = (float*)d_ws;

    // workspace layout (floats)
    float* a1   = ws;                 // 1,537,600  [50,32,31,31]
    float* a2   = a1 + 1537600;       //   627,200  [50,64,14,14]
    float* a3   = a2 + 627200;        //   230,400  [50,128,6,6]
    float* flat = a3 + 230400;        //    51,200  [50,1024]
    float* z    = flat + 51200;       //    25,600  [50,512]
    float* fc2o = z + 25600;          //    51,200  [50,1024]
    float* hbuf = fc2o + 51200;       //    51,200
    float* cbuf = hbuf + 51200;       //    51,200
    float* outs = cbuf + 51200;       //   870,400  [17,50,1024]
    float* hd   = outs + 870400;      //   870,400  [850,1024]
    float* wsum = hd + 870400;        // 4,194,304
    float* bsum = wsum + 4194304;     //     4,096
    float* wp2  = bsum + 4096;        //   393,216
    float* wp3  = wp2 + 393216;       //    98,304
    float* wp4  = wp3 + 98304;        //     1,536
    float* y1   = wp4 + 1536;         // 2,720,000  [850,128,5,5]
    float* y2   = y1 + 2720000;       // 9,193,600  [850,64,13,13]
    float* y3   = y2 + 9193600;       // 24,480,000 [850,32,30,30]
    float* g16  = y1;                 // 16*204,800 floats; y1/y2 dead during LSTM

    const int B = 50;
    const long GP = 204800;  // per-part stride in g16

    // prep
    addvec_kernel<<<(4194304+255)/256, 256, 0, stream>>>(w_ih, w_hh, wsum, 4194304);
    addvec_kernel<<<(4096+255)/256, 256, 0, stream>>>(b_ih, b_hh, bsum, 4096);
    wprep_kernel<<<(4*128*64*12+255)/256, 256, 0, stream>>>(d2_w, wp2, 128, 64, 5);
    wprep_kernel<<<(4*64*32*12+255)/256, 256, 0, stream>>>(d3_w, wp3, 64, 32, 6);
    wprep_kernel<<<(4*32*1*12+255)/256, 256, 0, stream>>>(d4_w, wp4, 32, 1, 6);

    // encoder
    conv_enc_kernel<1,32><<<(B*32*31*31+255)/256, 256, 0, stream>>>(x, conv1_w, conv1_b, a1, B, 64, 31);
    conv_enc_kernel<32,64><<<(B*64*14*14+255)/256, 256, 0, stream>>>(a1, conv2_w, conv2_b, a2, B, 31, 14);
    conv_enc_kernel<64,128><<<(B*128*6*6+255)/256, 256, 0, stream>>>(a2, conv3_w, conv3_b, a3, B, 14, 6);
    conv_enc_kernel<128,256><<<(B*256*2*2+255)/256, 256, 0, stream>>>(a3, conv4_w, conv4_b, flat, B, 6, 2);

    // fc1 -> z[:, :482]; action -> z[:, 482:512]; reward head
    {
        dim3 grid((482+63)/64, (B+31)/32, 1);
        gemm_kernel<32,64,32,true,0><<<grid, 128, 0, stream>>>(flat, fc1_w, fc1_b, z, B, 482, 1024, 1024, 512, 1, 0);
    }
    concat_action_kernel<<<(1500+63)/64, 64, 0, stream>>>(action, z);
    reward_kernel<<<1, 64, 0, stream>>>(z, fc5_w, fc5_b, out + (size_t)850*4096);

    // fc2 (leaky relu)
    {
        dim3 grid((1024+63)/64, (B+31)/32, 1);
        gemm_kernel<32,64,32,true,2><<<grid, 128, 0, stream>>>(z, fc2_w, fc2_b, fc2o, B, 1024, 512, 512, 1024, 1, 0);
    }

    // LSTM, 17 steps, split-K 16 partials in g16 (dead y1/y2 region)
    {
        dim3 grid0(64, 2, 8);
        gemm_kernel<32,64,32,true,0><<<grid0, 128, 0, stream>>>(fc2o, w_ih, nullptr, g16, B, 4096, 1024, 128, 4096, 1, GP);
        gemm_kernel<32,64,32,true,0><<<grid0, 128, 0, stream>>>(h0, w_hh, nullptr, g16 + 8*GP, B, 4096, 1024, 128, 4096, 1, GP);
        lstm_gates16_kernel<<<200, 256, 0, stream>>>(g16, bsum, c0, cbuf, hbuf, outs);
        dim3 gridt(64, 2, 16);
        for (int t = 1; t < 17; ++t) {
            gemm_kernel<32,64,32,true,0><<<gridt, 128, 0, stream>>>(hbuf, wsum, nullptr, g16, B, 4096, 1024, 64, 4096, 1, GP);
            lstm_gates16_kernel<<<200, 256, 0, stream>>>(g16, bsum, cbuf, cbuf, hbuf, outs + (size_t)t*51200);
        }
    }

    // fcsd: hd = leaky(outs @ fcsd_w^T + fcsd_b)   [850,1024]
    {
        dim3 grid((1024+63)/64, (850+63)/64, 1);
        gemm_kernel<64,64,32,true,2><<<grid, 256, 0, stream>>>(outs, fcsd_w, fcsd_b, hd, 850, 1024, 1024, 1024, 1024, 1, 0);
    }
    // d1: 1x1 spatial input -> pure GEMM [850,1024]x[1024,3200], tanh
    {
        dim3 grid((3200+63)/64, (850+63)/64, 1);
        gemm_kernel<64,64,32,false,1><<<grid, 256, 0, stream>>>(hd, d1_w, d1_b, y1, 850, 3200, 1024, 1024, 3200, 25, 0);
    }

    // d2: CIN=128,COUT=64,HIN=5,HOUT=13; no v-split, VPER=2 (NVB=4), TWU=7
    deconv4_kernel<128,64,5,13,1, 1,12,7,2,1,4><<<850, 256, 0, stream>>>(y1, wp2, d2_b, y2);
    // d3: CIN=64,COUT=32,HIN=13,HOUT=30; v-split 2, TWU=15
    deconv4_kernel<64,32,13,30,1, 2,20,15,1,1,3><<<1700, 256, 0, stream>>>(y2, wp3, d3_b, y3);
    // d4: CIN=32,COUT=1,HIN=30,HOUT=64; v-split 4, TWU=1, TB=32
    deconv4_kernel<32,1,30,64,0, 4,36,1,1,32,3><<<3400, 256, 0, stream>>>(y3, wp4, d4_b, out);

    (void)in_sizes; (void)n_in; (void)out_size; (void)ws_size;
}